// Round 10
// baseline (285.819 us; speedup 1.0000x reference)
//
#include <hip/hip_runtime.h>
#include <math.h>

// Problem constants (fixed by the reference file)
#define NPOINTS   8192
#define NDIM      64
#define TILE      128          // pairwise output tile per block
#define NT2       64           // NPOINTS / TILE
#define NBLK      2080         // NT2*(NT2+1)/2 triangle tiles
#define NGRP      512          // NPOINTS / 16 row-groups (prep blocks)

// ws dword/float layout:
//  [0, 262144)        W16f  : W as bf16 in MFMA-fragment order (see r9 comment)
//  [262144, 393216)   W8    : W as fp8 e4m3, packed 4/dword (8192 rows x 16 dwords = 64B/row)
//  [393216, 401408)   sq    : row squared norms (fp32 exact)
//  [401408, 403488)   partA : per-tile partials of sum 1/(1+d2) over a<b  (2080)
//  [403488, 411680)   a1p   : per-pair-block partials of sum pij*log(pij*(64+d2)) (8192)
//  [411680, 419872)   a3p   : per-pair-block partials of sum pij                  (8192)
//  [419872]           cnt   : last-block-finisher counter (zeroed by prep each call)
#define WS_W16   0
#define WS_W8    262144
#define WS_SQ    393216
#define WS_PARTA 401408
#define WS_A1P   403488
#define WS_A3P   411680
#define WS_CNT   419872

typedef __attribute__((ext_vector_type(8))) short bf16x8;   // 8 bf16 = 4 VGPRs (MFMA A/B frag)
typedef __attribute__((ext_vector_type(4))) float f32x4;    // MFMA C/D frag
typedef __attribute__((ext_vector_type(2))) float f32x2;

__device__ inline unsigned f2bf_pk(float lo, float hi) {    // pack 2 fp32 -> 2 bf16 (RNE)
    unsigned ul = __float_as_uint(lo), uh = __float_as_uint(hi);
    ul += 0x7FFFu + ((ul >> 16) & 1u);
    uh += 0x7FFFu + ((uh >> 16) & 1u);
    return (ul >> 16) | (uh & 0xFFFF0000u);
}
template <bool HI>
__device__ inline f32x2 cvt2(unsigned dw) {                 // 2 fp8 e4m3 -> 2 fp32 (HW cvt)
    return __builtin_amdgcn_cvt_pk_f32_fp8((int)dw, HI);    // word-sel must be constexpr
}
__device__ inline void sqacc(f32x2& s, unsigned a, unsigned b) {  // s += (deq(a)-deq(b))^2
    f32x2 dl = cvt2<false>(a) - cvt2<false>(b);
    f32x2 dh = cvt2<true >(a) - cvt2<true >(b);
    s += dl * dl;
    s += dh * dh;
}

// One block per 16-row group g: emits (1) W16f fragment-order bf16, (2) exact
// fp32 row norms, (3) fp8 rows. Block 0 also zeroes the finisher counter.
__global__ __launch_bounds__(256) void prep_kernel(const float* __restrict__ W,
                                                   float* __restrict__ sq,
                                                   unsigned* __restrict__ W16f,
                                                   unsigned* __restrict__ W8,
                                                   unsigned* __restrict__ cnt) {
    int g = blockIdx.x;
    int t = threadIdx.x;
    if (g == 0 && t == 0) *cnt = 0u;

    // ---- (1) fragment-order bf16: thread t -> (h, L, dpair), 4 floats -> uint2
    {
        int h = t >> 7, L = (t >> 1) & 63, dp = t & 1;
        int row = g * 16 + (L & 15), quad = L >> 4;
        float4 v = *(const float4*)(W + row * NDIM + h * 32 + quad * 8 + dp * 4);
        uint2 o;
        o.x = f2bf_pk(v.x, v.y);
        o.y = f2bf_pk(v.z, v.w);
        *(uint2*)(W16f + ((g * 2 + h) * 256 + L * 4 + dp * 2)) = o;
    }
    // ---- (2) exact row norms: thread t -> row r=t>>4, slice s=t&15 (4 elems)
    {
        int r = t >> 4, s = t & 15;
        float4 v = *(const float4*)(W + (g * 16 + r) * NDIM + s * 4);
        float p = v.x * v.x + v.y * v.y + v.z * v.z + v.w * v.w;
        p += __shfl_xor(p, 1, 64);
        p += __shfl_xor(p, 2, 64);
        p += __shfl_xor(p, 4, 64);
        p += __shfl_xor(p, 8, 64);
        if (s == 0) sq[g * 16 + r] = p;
    }
    // ---- (3) fp8 rows: thread t -> row t>>4, dword t&15
    {
        int r = g * 16 + (t >> 4), d = t & 15;
        float4 x = *(const float4*)(W + r * NDIM + d * 4);
        int lo = __builtin_amdgcn_cvt_pk_fp8_f32(x.x, x.y, 0, false);
        int dw = __builtin_amdgcn_cvt_pk_fp8_f32(x.z, x.w, lo, true);
        W8[r * 16 + d] = (unsigned)dw;
    }
}

// Merged main kernel:
//   zb <  NBLK : 128x128 MFMA triangle tile (r9 structure, swizzled frag loads)
//   zb >= NBLK : 64 sampled pairs (4 waves x 16), 4 lanes/pair on fp8 rows
//                (one 64B line per row; 4 contiguous lanes merge to 1 line request)
// Last block to finish reduces all partials (agent-scope loads) and writes out.
__global__ __launch_bounds__(256) void main_kernel(const unsigned* __restrict__ W16f,
                                                   const unsigned* __restrict__ W8,
                                                   const float* __restrict__ sq,
                                                   const float* __restrict__ pij,
                                                   const int* __restrict__ ii,
                                                   const int* __restrict__ jj,
                                                   int nb,
                                                   float* __restrict__ partA,
                                                   float* __restrict__ a1p,
                                                   float* __restrict__ a3p,
                                                   unsigned* __restrict__ cnt,
                                                   float* __restrict__ out) {
    __shared__ float red[8];
    __shared__ bool  lastflag;
    int zb = blockIdx.x;
    int t = threadIdx.x, w = t >> 6, lane = t & 63;

    if (zb < NBLK) {
        // ---------------- pairwise MFMA path ----------------
        int z = zb;
        int by = (int)((129.0f - sqrtf((float)(16641 - 8 * z))) * 0.5f);
        while (by * NT2 - by * (by - 1) / 2 > z) --by;
        while ((by + 1) * NT2 - (by + 1) * by / 2 <= z) ++by;
        int bx = by + (z - (by * NT2 - by * (by - 1) / 2));

        int wm = w >> 1, wn = w & 1, quad = lane >> 4, l15 = lane & 15;
        int a0 = by * TILE, b0 = bx * TILE;

        float4 base1[4];
        float  sqb[4];
        {
            int arow = a0 + wm * 64 + quad * 4;
            #pragma unroll
            for (int tm = 0; tm < 4; ++tm) {
                float4 v = *(const float4*)(sq + arow + tm * 16);
                base1[tm] = (float4){1.0f + v.x, 1.0f + v.y, 1.0f + v.z, 1.0f + v.w};
            }
            int bcol = b0 + wn * 64 + l15;
            #pragma unroll
            for (int tn = 0; tn < 4; ++tn) sqb[tn] = sq[bcol + tn * 16];
        }

        f32x4 acc[4][4];
        #pragma unroll
        for (int i = 0; i < 4; ++i)
            #pragma unroll
            for (int j = 0; j < 4; ++j) acc[i][j] = (f32x4){0.f, 0.f, 0.f, 0.f};

        int gA = (a0 >> 4) + wm * 4;
        int gB = (b0 >> 4) + wn * 4;
        #pragma unroll
        for (int h = 0; h < 2; ++h) {    // two K=32 halves; 1 KB contiguous per frag
            bf16x8 af[4], bfr[4];
            #pragma unroll
            for (int tm = 0; tm < 4; ++tm)
                af[tm] = *(const bf16x8*)(W16f + (((gA + tm) * 2 + h) * 256 + lane * 4));
            #pragma unroll
            for (int tn = 0; tn < 4; ++tn)
                bfr[tn] = *(const bf16x8*)(W16f + (((gB + tn) * 2 + h) * 256 + lane * 4));
            #pragma unroll
            for (int tm = 0; tm < 4; ++tm)
                #pragma unroll
                for (int tn = 0; tn < 4; ++tn)
                    acc[tm][tn] = __builtin_amdgcn_mfma_f32_16x16x32_bf16(af[tm], bfr[tn],
                                                                          acc[tm][tn], 0, 0, 0);
        }

        float ssum = 0.f;
        if (bx > by) {
            #pragma unroll
            for (int tn = 0; tn < 4; ++tn) {
                float c0 = sqb[tn];
                #pragma unroll
                for (int tm = 0; tm < 4; ++tm) {
                    ssum += __builtin_amdgcn_rcpf(fmaf(acc[tm][tn][0], -2.0f, base1[tm].x + c0));
                    ssum += __builtin_amdgcn_rcpf(fmaf(acc[tm][tn][1], -2.0f, base1[tm].y + c0));
                    ssum += __builtin_amdgcn_rcpf(fmaf(acc[tm][tn][2], -2.0f, base1[tm].z + c0));
                    ssum += __builtin_amdgcn_rcpf(fmaf(acc[tm][tn][3], -2.0f, base1[tm].w + c0));
                }
            }
        } else {                         // diagonal tile: strictly-upper only
            int quad4 = quad * 4;
            #pragma unroll
            for (int tn = 0; tn < 4; ++tn) {
                int cl = wn * 64 + tn * 16 + l15;
                float c0 = sqb[tn];
                float b4[4];
                #pragma unroll
                for (int tm = 0; tm < 4; ++tm) {
                    b4[0] = base1[tm].x; b4[1] = base1[tm].y;
                    b4[2] = base1[tm].z; b4[3] = base1[tm].w;
                    #pragma unroll
                    for (int r = 0; r < 4; ++r) {
                        int rl = wm * 64 + tm * 16 + quad4 + r;
                        float inv = __builtin_amdgcn_rcpf(fmaf(acc[tm][tn][r], -2.0f, b4[r] + c0));
                        ssum += (cl > rl) ? inv : 0.f;
                    }
                }
            }
        }
        #pragma unroll
        for (int m = 32; m >= 1; m >>= 1) ssum += __shfl_xor(ssum, m, 64);
        if (lane == 0) red[w] = ssum;
        __syncthreads();
        if (t == 0) partA[z] = red[0] + red[1] + red[2] + red[3];
    } else {
        // ------- pair path: 4 lanes/pair, fp8 rows, 2 line-requests/pair -------
        int pb = zb - NBLK;              // pair block id
        int g  = lane >> 2;              // pair slot in wave (0..15)
        int s  = lane & 3;               // 16B chunk slot within the 64B row
        int p  = pb * 64 + w * 16 + g;
        float a1 = 0.f, a3 = 0.f;
        if (p < nb) {
            int   i  = ii[p];            // 4-lane redundant; wave reads 16 consecutive
            int   j  = jj[p];
            float pv = pij[p];
            uint4 xi = *(const uint4*)(W8 + i * 16 + s * 4);
            uint4 xj = *(const uint4*)(W8 + j * 16 + s * 4);
            f32x2 s2 = {0.f, 0.f};
            sqacc(s2, xi.x, xj.x);
            sqacc(s2, xi.y, xj.y);
            sqacc(s2, xi.z, xj.z);
            sqacc(s2, xi.w, xj.w);
            float v = s2.x + s2.y;       // this lane's 16-elem partial
            v += __shfl_xor(v, 1, 64);
            v += __shfl_xor(v, 2, 64);   // all 4 lanes: ||xi-xj||^2
            a1 = pv * __logf(pv * ((float)NDIM + v));
            a3 = pv;
        }
        #pragma unroll
        for (int m = 32; m >= 1; m >>= 1) {
            a1 += __shfl_xor(a1, m, 64);
            a3 += __shfl_xor(a3, m, 64);
        }
        if (lane == 0) { red[w] = a1 * 0.25f; red[4 + w] = a3 * 0.25f; }  // 4x redundancy
        __syncthreads();
        if (t == 0) {
            a1p[pb] = red[0] + red[1] + red[2] + red[3];
            a3p[pb] = red[4] + red[5] + red[6] + red[7];
        }
    }

    // ---------------- last-block finisher ----------------
    if (t == 0) {
        __threadfence();                                   // partials visible device-wide
        unsigned old = atomicAdd(cnt, 1u);                 // device-scope
        lastflag = (old == gridDim.x - 1);
    }
    __syncthreads();
    if (!lastflag) return;

    __shared__ double r1s[256], r2s[256], r3s[256];
    int npb = (int)gridDim.x - NBLK;
    double dpart = 0.0, d1 = 0.0, d3 = 0.0;
    for (int k = t; k < NBLK; k += 256)
        dpart += (double)__hip_atomic_load(&partA[k], __ATOMIC_RELAXED, __HIP_MEMORY_SCOPE_AGENT);
    for (int k = t; k < npb; k += 256) {
        d1 += (double)__hip_atomic_load(&a1p[k], __ATOMIC_RELAXED, __HIP_MEMORY_SCOPE_AGENT);
        d3 += (double)__hip_atomic_load(&a3p[k], __ATOMIC_RELAXED, __HIP_MEMORY_SCOPE_AGENT);
    }
    r1s[t] = dpart; r2s[t] = d1; r3s[t] = d3;
    __syncthreads();
    for (int s2 = 128; s2 >= 1; s2 >>= 1) {
        if (t < s2) { r1s[t] += r1s[t + s2]; r2s[t] += r2s[t + s2]; r3s[t] += r3s[t + s2]; }
        __syncthreads();
    }
    if (t == 0) {
        double part = 2.0 * r1s[0];      // sum over a<b, doubled; diagonal cancels -n
        out[0] = (float)(r2s[0] + r3s[0] * log(part));
    }
}

extern "C" void kernel_launch(void* const* d_in, const int* in_sizes, int n_in,
                              void* d_out, int out_size, void* d_ws, size_t ws_size,
                              hipStream_t stream) {
    const float* pij = (const float*)d_in[0];
    const int*   ii  = (const int*)d_in[1];
    const int*   jj  = (const int*)d_in[2];
    const float* W   = (const float*)d_in[3];
    float* out = (float*)d_out;
    float* ws  = (float*)d_ws;

    unsigned* W16f  = (unsigned*)ws + WS_W16;
    unsigned* W8    = (unsigned*)ws + WS_W8;
    float*    sqv   = ws + WS_SQ;
    float*    partA = ws + WS_PARTA;
    float*    a1p   = ws + WS_A1P;
    float*    a3p   = ws + WS_A3P;
    unsigned* cnt   = (unsigned*)ws + WS_CNT;

    int nb  = in_sizes[0];            // number of sampled pairs (B)
    int npb = (nb + 63) / 64;         // pair blocks (8192 for B=524288)

    prep_kernel<<<NGRP, 256, 0, stream>>>(W, sqv, W16f, W8, cnt);
    main_kernel<<<NBLK + npb, 256, 0, stream>>>(W16f, W8, sqv, pij, ii, jj, nb,
                                                partA, a1p, a3p, cnt, out);
}

// Round 11
// 103.802 us; speedup vs baseline: 2.7535x; 2.7535x over previous
//
#include <hip/hip_runtime.h>
#include <math.h>

// Problem constants (fixed by the reference file)
#define NPOINTS   8192
#define NDIM      64
#define TILE      128          // pairwise output tile per block
#define NT2       64           // NPOINTS / TILE
#define NBLK      2080         // NT2*(NT2+1)/2 triangle tiles
#define NGRP      512          // NPOINTS / 16 row-groups (prep blocks)

// ws dword/float layout:
//  [0, 262144)        W16f  : W as bf16 in MFMA-fragment order (see r9 comment)
//  [262144, 393216)   W8    : W as fp8 e4m3, packed 4/dword (8192 rows x 16 dwords = 64B/row)
//  [393216, 401408)   sq    : row squared norms (fp32 exact)
//  [401408, 403488)   partA : per-tile partials of sum 1/(1+d2) over a<b  (2080)
//  [403488, 411680)   a1p   : per-pair-block partials of sum pij*log(pij*(64+d2)) (8192)
//  [411680, 419872)   a3p   : per-pair-block partials of sum pij                  (8192)
#define WS_W16   0
#define WS_W8    262144
#define WS_SQ    393216
#define WS_PARTA 401408
#define WS_A1P   403488
#define WS_A3P   411680

typedef __attribute__((ext_vector_type(8))) short bf16x8;   // 8 bf16 = 4 VGPRs (MFMA A/B frag)
typedef __attribute__((ext_vector_type(4))) float f32x4;    // MFMA C/D frag
typedef __attribute__((ext_vector_type(2))) float f32x2;

__device__ inline unsigned f2bf_pk(float lo, float hi) {    // pack 2 fp32 -> 2 bf16 (RNE)
    unsigned ul = __float_as_uint(lo), uh = __float_as_uint(hi);
    ul += 0x7FFFu + ((ul >> 16) & 1u);
    uh += 0x7FFFu + ((uh >> 16) & 1u);
    return (ul >> 16) | (uh & 0xFFFF0000u);
}
template <bool HI>
__device__ inline f32x2 cvt2(unsigned dw) {                 // 2 fp8 e4m3 -> 2 fp32 (HW cvt)
    return __builtin_amdgcn_cvt_pk_f32_fp8((int)dw, HI);    // word-sel must be constexpr
}
__device__ inline void sqacc(f32x2& s, unsigned a, unsigned b) {  // s += (deq(a)-deq(b))^2
    f32x2 dl = cvt2<false>(a) - cvt2<false>(b);
    f32x2 dh = cvt2<true >(a) - cvt2<true >(b);
    s += dl * dl;
    s += dh * dh;
}

// One block per 16-row group g: emits (1) W16f fragment-order bf16, (2) exact
// fp32 row norms, (3) fp8 rows. All loads/stores coalesced.
__global__ __launch_bounds__(256) void prep_kernel(const float* __restrict__ W,
                                                   float* __restrict__ sq,
                                                   unsigned* __restrict__ W16f,
                                                   unsigned* __restrict__ W8) {
    int g = blockIdx.x;
    int t = threadIdx.x;

    // ---- (1) fragment-order bf16: thread t -> (h, L, dpair), 4 floats -> uint2
    {
        int h = t >> 7, L = (t >> 1) & 63, dp = t & 1;
        int row = g * 16 + (L & 15), quad = L >> 4;
        float4 v = *(const float4*)(W + row * NDIM + h * 32 + quad * 8 + dp * 4);
        uint2 o;
        o.x = f2bf_pk(v.x, v.y);
        o.y = f2bf_pk(v.z, v.w);
        *(uint2*)(W16f + ((g * 2 + h) * 256 + L * 4 + dp * 2)) = o;
    }
    // ---- (2) exact row norms: thread t -> row r=t>>4, slice s=t&15 (4 elems)
    {
        int r = t >> 4, s = t & 15;
        float4 v = *(const float4*)(W + (g * 16 + r) * NDIM + s * 4);
        float p = v.x * v.x + v.y * v.y + v.z * v.z + v.w * v.w;
        p += __shfl_xor(p, 1, 64);
        p += __shfl_xor(p, 2, 64);
        p += __shfl_xor(p, 4, 64);
        p += __shfl_xor(p, 8, 64);
        if (s == 0) sq[g * 16 + r] = p;
    }
    // ---- (3) fp8 rows: thread t -> row t>>4, dword t&15
    {
        int r = g * 16 + (t >> 4), d = t & 15;
        float4 x = *(const float4*)(W + r * NDIM + d * 4);
        int lo = __builtin_amdgcn_cvt_pk_fp8_f32(x.x, x.y, 0, false);
        int dw = __builtin_amdgcn_cvt_pk_fp8_f32(x.z, x.w, lo, true);
        W8[r * 16 + d] = (unsigned)dw;
    }
}

// Merged main kernel (NO finisher — plain per-block partial stores):
//   zb <  NBLK : 128x128 MFMA triangle tile (r9 structure, swizzled frag loads)
//   zb >= NBLK : 64 sampled pairs (4 waves x 16), 4 lanes/pair on fp8 rows
//                (row = one 64B line; 4 contiguous lanes merge to 1 line request)
__global__ __launch_bounds__(256) void main_kernel(const unsigned* __restrict__ W16f,
                                                   const unsigned* __restrict__ W8,
                                                   const float* __restrict__ sq,
                                                   const float* __restrict__ pij,
                                                   const int* __restrict__ ii,
                                                   const int* __restrict__ jj,
                                                   int nb,
                                                   float* __restrict__ partA,
                                                   float* __restrict__ a1p,
                                                   float* __restrict__ a3p) {
    __shared__ float red[8];
    int zb = blockIdx.x;
    int t = threadIdx.x, w = t >> 6, lane = t & 63;

    if (zb < NBLK) {
        // ---------------- pairwise MFMA path ----------------
        int z = zb;
        int by = (int)((129.0f - sqrtf((float)(16641 - 8 * z))) * 0.5f);
        while (by * NT2 - by * (by - 1) / 2 > z) --by;
        while ((by + 1) * NT2 - (by + 1) * by / 2 <= z) ++by;
        int bx = by + (z - (by * NT2 - by * (by - 1) / 2));

        int wm = w >> 1, wn = w & 1, quad = lane >> 4, l15 = lane & 15;
        int a0 = by * TILE, b0 = bx * TILE;

        float4 base1[4];
        float  sqb[4];
        {
            int arow = a0 + wm * 64 + quad * 4;
            #pragma unroll
            for (int tm = 0; tm < 4; ++tm) {
                float4 v = *(const float4*)(sq + arow + tm * 16);
                base1[tm] = (float4){1.0f + v.x, 1.0f + v.y, 1.0f + v.z, 1.0f + v.w};
            }
            int bcol = b0 + wn * 64 + l15;
            #pragma unroll
            for (int tn = 0; tn < 4; ++tn) sqb[tn] = sq[bcol + tn * 16];
        }

        f32x4 acc[4][4];
        #pragma unroll
        for (int i = 0; i < 4; ++i)
            #pragma unroll
            for (int j = 0; j < 4; ++j) acc[i][j] = (f32x4){0.f, 0.f, 0.f, 0.f};

        int gA = (a0 >> 4) + wm * 4;
        int gB = (b0 >> 4) + wn * 4;
        #pragma unroll
        for (int h = 0; h < 2; ++h) {    // two K=32 halves; 1 KB contiguous per frag
            bf16x8 af[4], bfr[4];
            #pragma unroll
            for (int tm = 0; tm < 4; ++tm)
                af[tm] = *(const bf16x8*)(W16f + (((gA + tm) * 2 + h) * 256 + lane * 4));
            #pragma unroll
            for (int tn = 0; tn < 4; ++tn)
                bfr[tn] = *(const bf16x8*)(W16f + (((gB + tn) * 2 + h) * 256 + lane * 4));
            #pragma unroll
            for (int tm = 0; tm < 4; ++tm)
                #pragma unroll
                for (int tn = 0; tn < 4; ++tn)
                    acc[tm][tn] = __builtin_amdgcn_mfma_f32_16x16x32_bf16(af[tm], bfr[tn],
                                                                          acc[tm][tn], 0, 0, 0);
        }

        float ssum = 0.f;
        if (bx > by) {
            #pragma unroll
            for (int tn = 0; tn < 4; ++tn) {
                float c0 = sqb[tn];
                #pragma unroll
                for (int tm = 0; tm < 4; ++tm) {
                    ssum += __builtin_amdgcn_rcpf(fmaf(acc[tm][tn][0], -2.0f, base1[tm].x + c0));
                    ssum += __builtin_amdgcn_rcpf(fmaf(acc[tm][tn][1], -2.0f, base1[tm].y + c0));
                    ssum += __builtin_amdgcn_rcpf(fmaf(acc[tm][tn][2], -2.0f, base1[tm].z + c0));
                    ssum += __builtin_amdgcn_rcpf(fmaf(acc[tm][tn][3], -2.0f, base1[tm].w + c0));
                }
            }
        } else {                         // diagonal tile: strictly-upper only
            int quad4 = quad * 4;
            #pragma unroll
            for (int tn = 0; tn < 4; ++tn) {
                int cl = wn * 64 + tn * 16 + l15;
                float c0 = sqb[tn];
                float b4[4];
                #pragma unroll
                for (int tm = 0; tm < 4; ++tm) {
                    b4[0] = base1[tm].x; b4[1] = base1[tm].y;
                    b4[2] = base1[tm].z; b4[3] = base1[tm].w;
                    #pragma unroll
                    for (int r = 0; r < 4; ++r) {
                        int rl = wm * 64 + tm * 16 + quad4 + r;
                        float inv = __builtin_amdgcn_rcpf(fmaf(acc[tm][tn][r], -2.0f, b4[r] + c0));
                        ssum += (cl > rl) ? inv : 0.f;
                    }
                }
            }
        }
        #pragma unroll
        for (int m = 32; m >= 1; m >>= 1) ssum += __shfl_xor(ssum, m, 64);
        if (lane == 0) red[w] = ssum;
        __syncthreads();
        if (t == 0) partA[z] = red[0] + red[1] + red[2] + red[3];
    } else {
        // ------- pair path: 4 lanes/pair, fp8 rows, 2 line-requests/pair -------
        int pb = zb - NBLK;              // pair block id
        int g  = lane >> 2;              // pair slot in wave (0..15)
        int s  = lane & 3;               // 16B chunk slot within the 64B row
        int p  = pb * 64 + w * 16 + g;
        float a1 = 0.f, a3 = 0.f;
        if (p < nb) {
            int   i  = ii[p];            // 4-lane redundant; wave reads 16 consecutive
            int   j  = jj[p];
            float pv = pij[p];
            uint4 xi = *(const uint4*)(W8 + i * 16 + s * 4);
            uint4 xj = *(const uint4*)(W8 + j * 16 + s * 4);
            f32x2 s2 = {0.f, 0.f};
            sqacc(s2, xi.x, xj.x);
            sqacc(s2, xi.y, xj.y);
            sqacc(s2, xi.z, xj.z);
            sqacc(s2, xi.w, xj.w);
            float v = s2.x + s2.y;       // this lane's 16-elem partial
            v += __shfl_xor(v, 1, 64);
            v += __shfl_xor(v, 2, 64);   // all 4 lanes: ||xi-xj||^2
            a1 = pv * __logf(pv * ((float)NDIM + v));
            a3 = pv;
        }
        #pragma unroll
        for (int m = 32; m >= 1; m >>= 1) {
            a1 += __shfl_xor(a1, m, 64);
            a3 += __shfl_xor(a3, m, 64);
        }
        if (lane == 0) { red[w] = a1 * 0.25f; red[4 + w] = a3 * 0.25f; }  // 4x redundancy
        __syncthreads();
        if (t == 0) {
            a1p[pb] = red[0] + red[1] + red[2] + red[3];
            a3p[pb] = red[4] + red[5] + red[6] + red[7];
        }
    }
}

__global__ __launch_bounds__(256) void final_kernel(const float* __restrict__ partA,
                                                    const float* __restrict__ a1p,
                                                    const float* __restrict__ a3p,
                                                    int npb,
                                                    float* __restrict__ out) {
    __shared__ double r1[256], r2[256], r3[256];
    int t = threadIdx.x;
    double dpart = 0.0, d1 = 0.0, d3 = 0.0;
    for (int k = t; k < NBLK; k += 256) dpart += (double)partA[k];
    for (int k = t; k < npb; k += 256) { d1 += (double)a1p[k]; d3 += (double)a3p[k]; }
    r1[t] = dpart; r2[t] = d1; r3[t] = d3;
    __syncthreads();
    for (int s = 128; s >= 1; s >>= 1) {
        if (t < s) { r1[t] += r1[t + s]; r2[t] += r2[t + s]; r3[t] += r3[t + s]; }
        __syncthreads();
    }
    if (t == 0) {
        double part = 2.0 * r1[0];                 // sum over a<b, doubled; diagonal cancels -n
        out[0] = (float)(r2[0] + r3[0] * log(part));
    }
}

extern "C" void kernel_launch(void* const* d_in, const int* in_sizes, int n_in,
                              void* d_out, int out_size, void* d_ws, size_t ws_size,
                              hipStream_t stream) {
    const float* pij = (const float*)d_in[0];
    const int*   ii  = (const int*)d_in[1];
    const int*   jj  = (const int*)d_in[2];
    const float* W   = (const float*)d_in[3];
    float* out = (float*)d_out;
    float* ws  = (float*)d_ws;

    unsigned* W16f  = (unsigned*)ws + WS_W16;
    unsigned* W8    = (unsigned*)ws + WS_W8;
    float*    sqv   = ws + WS_SQ;
    float*    partA = ws + WS_PARTA;
    float*    a1p   = ws + WS_A1P;
    float*    a3p   = ws + WS_A3P;

    int nb  = in_sizes[0];            // number of sampled pairs (B)
    int npb = (nb + 63) / 64;         // pair blocks (8192 for B=524288)

    prep_kernel<<<NGRP, 256, 0, stream>>>(W, sqv, W16f, W8);
    main_kernel<<<NBLK + npb, 256, 0, stream>>>(W16f, W8, sqv, pij, ii, jj, nb,
                                                partA, a1p, a3p);
    final_kernel<<<1, 256, 0, stream>>>(partA, a1p, a3p, npb, out);
}

// Round 12
// 97.266 us; speedup vs baseline: 2.9385x; 1.0672x over previous
//
#include <hip/hip_runtime.h>
#include <math.h>

// Problem constants (fixed by the reference file)
#define NPOINTS   8192
#define NDIM      64
#define TILE      128          // pairwise output tile per block
#define NT2       64           // NPOINTS / TILE
#define NBLK      2080         // NT2*(NT2+1)/2 triangle tiles
#define NGRP      512          // NPOINTS / 16 row-groups (prep blocks)

// ws dword/float layout:
//  [0, 262144)        W16f  : W as bf16 in MFMA-fragment order (see r9 comment)
//  [262144, 393216)   W8    : W as fp8 e4m3, packed 4/dword (8192 rows x 16 dwords = 64B/row)
//  [393216, 401408)   sq    : row squared norms (fp32 exact)
//  [401408, 403488)   partA : per-tile partials of sum 1/(1+d2) over a<b  (2080)
//  [403488, 411680)   a1p   : per-pair-block partials of sum pij*log(pij*(64+d2)) (8192)
//  [411680, 419872)   a3p   : per-pair-block partials of sum pij                  (8192)
#define WS_W16   0
#define WS_W8    262144
#define WS_SQ    393216
#define WS_PARTA 401408
#define WS_A1P   403488
#define WS_A3P   411680

typedef __attribute__((ext_vector_type(8))) short bf16x8;   // 8 bf16 = 4 VGPRs (MFMA A/B frag)
typedef __attribute__((ext_vector_type(4))) float f32x4;    // MFMA C/D frag
typedef __attribute__((ext_vector_type(2))) float f32x2;

__device__ inline unsigned f2bf_pk(float lo, float hi) {    // pack 2 fp32 -> 2 bf16 (RNE)
    unsigned ul = __float_as_uint(lo), uh = __float_as_uint(hi);
    ul += 0x7FFFu + ((ul >> 16) & 1u);
    uh += 0x7FFFu + ((uh >> 16) & 1u);
    return (ul >> 16) | (uh & 0xFFFF0000u);
}
template <bool HI>
__device__ inline f32x2 cvt2(unsigned dw) {                 // 2 fp8 e4m3 -> 2 fp32 (HW cvt)
    return __builtin_amdgcn_cvt_pk_f32_fp8((int)dw, HI);    // word-sel must be constexpr
}
__device__ inline void sqacc(f32x2& s, unsigned a, unsigned b) {  // s += (deq(a)-deq(b))^2
    f32x2 dl = cvt2<false>(a) - cvt2<false>(b);
    f32x2 dh = cvt2<true >(a) - cvt2<true >(b);
    s += dl * dl;
    s += dh * dh;
}

// One block per 16-row group g: emits (1) W16f fragment-order bf16, (2) exact
// fp32 row norms, (3) fp8 rows. All loads/stores coalesced.  (identical to r9)
__global__ __launch_bounds__(256) void prep_kernel(const float* __restrict__ W,
                                                   float* __restrict__ sq,
                                                   unsigned* __restrict__ W16f,
                                                   unsigned* __restrict__ W8) {
    int g = blockIdx.x;
    int t = threadIdx.x;

    // ---- (1) fragment-order bf16: thread t -> (h, L, dpair), 4 floats -> uint2
    {
        int h = t >> 7, L = (t >> 1) & 63, dp = t & 1;
        int row = g * 16 + (L & 15), quad = L >> 4;
        float4 v = *(const float4*)(W + row * NDIM + h * 32 + quad * 8 + dp * 4);
        uint2 o;
        o.x = f2bf_pk(v.x, v.y);
        o.y = f2bf_pk(v.z, v.w);
        *(uint2*)(W16f + ((g * 2 + h) * 256 + L * 4 + dp * 2)) = o;
    }
    // ---- (2) exact row norms: thread t -> row r=t>>4, slice s=t&15 (4 elems)
    {
        int r = t >> 4, s = t & 15;
        float4 v = *(const float4*)(W + (g * 16 + r) * NDIM + s * 4);
        float p = v.x * v.x + v.y * v.y + v.z * v.z + v.w * v.w;
        p += __shfl_xor(p, 1, 64);
        p += __shfl_xor(p, 2, 64);
        p += __shfl_xor(p, 4, 64);
        p += __shfl_xor(p, 8, 64);
        if (s == 0) sq[g * 16 + r] = p;
    }
    // ---- (3) fp8 rows: thread t -> row t>>4, dword t&15
    {
        int r = g * 16 + (t >> 4), d = t & 15;
        float4 x = *(const float4*)(W + r * NDIM + d * 4);
        int lo = __builtin_amdgcn_cvt_pk_fp8_f32(x.x, x.y, 0, false);
        int dw = __builtin_amdgcn_cvt_pk_fp8_f32(x.z, x.w, lo, true);
        W8[r * 16 + d] = (unsigned)dw;
    }
}

// Pair kernel, 4 lanes per pair (16 pairs/wave, 64/block, one shot):
// an fp8 row is one 64B line; 4 contiguous lanes x 16B merge into ONE line
// request -> 2 line-requests per pair (vs 8 for 1-thread/pair).
__global__ __launch_bounds__(256) void pair_kernel(const unsigned* __restrict__ W8,
                                                   const float* __restrict__ pij,
                                                   const int* __restrict__ ii,
                                                   const int* __restrict__ jj,
                                                   int nb,
                                                   float* __restrict__ a1p,
                                                   float* __restrict__ a3p) {
    int t = threadIdx.x, w = t >> 6, lane = t & 63;
    int g = lane >> 2;               // pair slot in wave (0..15)
    int s = lane & 3;                // 16B chunk slot within the 64B row
    int p = blockIdx.x * 64 + w * 16 + g;
    float a1 = 0.f, a3 = 0.f;
    if (p < nb) {
        int   i  = ii[p];            // wave reads 16 consecutive ints (4x redundant)
        int   j  = jj[p];
        float pv = pij[p];
        uint4 xi = *(const uint4*)(W8 + i * 16 + s * 4);
        uint4 xj = *(const uint4*)(W8 + j * 16 + s * 4);
        f32x2 s2 = {0.f, 0.f};
        sqacc(s2, xi.x, xj.x);
        sqacc(s2, xi.y, xj.y);
        sqacc(s2, xi.z, xj.z);
        sqacc(s2, xi.w, xj.w);
        float v = s2.x + s2.y;       // this lane's 16-elem partial
        v += __shfl_xor(v, 1, 64);
        v += __shfl_xor(v, 2, 64);   // all 4 lanes: ||xi-xj||^2
        a1 = pv * __logf(pv * ((float)NDIM + v));
        a3 = pv;
    }
    #pragma unroll
    for (int m = 32; m >= 1; m >>= 1) {
        a1 += __shfl_xor(a1, m, 64);
        a3 += __shfl_xor(a3, m, 64);
    }
    __shared__ float red[8];
    if (lane == 0) { red[w] = a1 * 0.25f; red[4 + w] = a3 * 0.25f; }  // 4x redundancy
    __syncthreads();
    if (t == 0) {
        a1p[blockIdx.x] = red[0] + red[1] + red[2] + red[3];
        a3p[blockIdx.x] = red[4] + red[5] + red[6] + red[7];
    }
}

// 128x128 triangle tile of the Cauchy partition via bf16 MFMA, swizzled
// contiguous frag loads (identical to r9).
__global__ __launch_bounds__(256) void pairwise_kernel(const unsigned* __restrict__ W16f,
                                                       const float* __restrict__ sq,
                                                       float* __restrict__ partA) {
    int z = blockIdx.x;
    int t = threadIdx.x, w = t >> 6, lane = t & 63;
    int by = (int)((129.0f - sqrtf((float)(16641 - 8 * z))) * 0.5f);
    while (by * NT2 - by * (by - 1) / 2 > z) --by;
    while ((by + 1) * NT2 - (by + 1) * by / 2 <= z) ++by;
    int bx = by + (z - (by * NT2 - by * (by - 1) / 2));

    int wm = w >> 1, wn = w & 1, quad = lane >> 4, l15 = lane & 15;
    int a0 = by * TILE, b0 = bx * TILE;

    float4 base1[4];                 // 1 + sq[arow + tm*16 + 0..3]
    float  sqb[4];
    {
        int arow = a0 + wm * 64 + quad * 4;
        #pragma unroll
        for (int tm = 0; tm < 4; ++tm) {
            float4 v = *(const float4*)(sq + arow + tm * 16);
            base1[tm] = (float4){1.0f + v.x, 1.0f + v.y, 1.0f + v.z, 1.0f + v.w};
        }
        int bcol = b0 + wn * 64 + l15;
        #pragma unroll
        for (int tn = 0; tn < 4; ++tn) sqb[tn] = sq[bcol + tn * 16];
    }

    f32x4 acc[4][4];
    #pragma unroll
    for (int i = 0; i < 4; ++i)
        #pragma unroll
        for (int j = 0; j < 4; ++j) acc[i][j] = (f32x4){0.f, 0.f, 0.f, 0.f};

    int gA = (a0 >> 4) + wm * 4;     // A row-groups gA+tm; B row-groups gB+tn
    int gB = (b0 >> 4) + wn * 4;
    #pragma unroll
    for (int h = 0; h < 2; ++h) {    // two K=32 halves; 1 KB contiguous per frag
        bf16x8 af[4], bfr[4];
        #pragma unroll
        for (int tm = 0; tm < 4; ++tm)
            af[tm] = *(const bf16x8*)(W16f + (((gA + tm) * 2 + h) * 256 + lane * 4));
        #pragma unroll
        for (int tn = 0; tn < 4; ++tn)
            bfr[tn] = *(const bf16x8*)(W16f + (((gB + tn) * 2 + h) * 256 + lane * 4));
        #pragma unroll
        for (int tm = 0; tm < 4; ++tm)
            #pragma unroll
            for (int tn = 0; tn < 4; ++tn)
                acc[tm][tn] = __builtin_amdgcn_mfma_f32_16x16x32_bf16(af[tm], bfr[tn],
                                                                      acc[tm][tn], 0, 0, 0);
    }

    float ssum = 0.f;
    if (bx > by) {
        #pragma unroll
        for (int tn = 0; tn < 4; ++tn) {
            float c0 = sqb[tn];
            #pragma unroll
            for (int tm = 0; tm < 4; ++tm) {
                ssum += __builtin_amdgcn_rcpf(fmaf(acc[tm][tn][0], -2.0f, base1[tm].x + c0));
                ssum += __builtin_amdgcn_rcpf(fmaf(acc[tm][tn][1], -2.0f, base1[tm].y + c0));
                ssum += __builtin_amdgcn_rcpf(fmaf(acc[tm][tn][2], -2.0f, base1[tm].z + c0));
                ssum += __builtin_amdgcn_rcpf(fmaf(acc[tm][tn][3], -2.0f, base1[tm].w + c0));
            }
        }
    } else {                         // diagonal tile: strictly-upper only
        int quad4 = quad * 4;
        #pragma unroll
        for (int tn = 0; tn < 4; ++tn) {
            int cl = wn * 64 + tn * 16 + l15;
            float c0 = sqb[tn];
            float b4[4];
            #pragma unroll
            for (int tm = 0; tm < 4; ++tm) {
                b4[0] = base1[tm].x; b4[1] = base1[tm].y;
                b4[2] = base1[tm].z; b4[3] = base1[tm].w;
                #pragma unroll
                for (int r = 0; r < 4; ++r) {
                    int rl = wm * 64 + tm * 16 + quad4 + r;
                    float inv = __builtin_amdgcn_rcpf(fmaf(acc[tm][tn][r], -2.0f, b4[r] + c0));
                    ssum += (cl > rl) ? inv : 0.f;
                }
            }
        }
    }
    #pragma unroll
    for (int m = 32; m >= 1; m >>= 1) ssum += __shfl_xor(ssum, m, 64);
    __shared__ float wsum[4];
    if (lane == 0) wsum[w] = ssum;
    __syncthreads();
    if (t == 0) partA[z] = wsum[0] + wsum[1] + wsum[2] + wsum[3];
}

__global__ __launch_bounds__(256) void final_kernel(const float* __restrict__ partA,
                                                    const float* __restrict__ a1p,
                                                    const float* __restrict__ a3p,
                                                    int npb,
                                                    float* __restrict__ out) {
    __shared__ double r1[256], r2[256], r3[256];
    int t = threadIdx.x;
    double dpart = 0.0, d1 = 0.0, d3 = 0.0;
    for (int k = t; k < NBLK; k += 256) dpart += (double)partA[k];
    for (int k = t; k < npb; k += 256) { d1 += (double)a1p[k]; d3 += (double)a3p[k]; }
    r1[t] = dpart; r2[t] = d1; r3[t] = d3;
    __syncthreads();
    for (int s = 128; s >= 1; s >>= 1) {
        if (t < s) { r1[t] += r1[t + s]; r2[t] += r2[t + s]; r3[t] += r3[t + s]; }
        __syncthreads();
    }
    if (t == 0) {
        double part = 2.0 * r1[0];                 // sum over a<b, doubled; diagonal cancels -n
        out[0] = (float)(r2[0] + r3[0] * log(part));
    }
}

extern "C" void kernel_launch(void* const* d_in, const int* in_sizes, int n_in,
                              void* d_out, int out_size, void* d_ws, size_t ws_size,
                              hipStream_t stream) {
    const float* pij = (const float*)d_in[0];
    const int*   ii  = (const int*)d_in[1];
    const int*   jj  = (const int*)d_in[2];
    const float* W   = (const float*)d_in[3];
    float* out = (float*)d_out;
    float* ws  = (float*)d_ws;

    unsigned* W16f  = (unsigned*)ws + WS_W16;
    unsigned* W8    = (unsigned*)ws + WS_W8;
    float*    sqv   = ws + WS_SQ;
    float*    partA = ws + WS_PARTA;
    float*    a1p   = ws + WS_A1P;
    float*    a3p   = ws + WS_A3P;

    int nb  = in_sizes[0];            // number of sampled pairs (B)
    int npb = (nb + 63) / 64;         // pair blocks (8192 for B=524288)

    prep_kernel<<<NGRP, 256, 0, stream>>>(W, sqv, W16f, W8);
    pair_kernel<<<npb, 256, 0, stream>>>(W8, pij, ii, jj, nb, a1p, a3p);
    pairwise_kernel<<<NBLK, 256, 0, stream>>>(W16f, sqv, partA);
    final_kernel<<<1, 256, 0, stream>>>(partA, a1p, a3p, npb, out);
}

// Round 13
// 91.818 us; speedup vs baseline: 3.1129x; 1.0593x over previous
//
#include <hip/hip_runtime.h>
#include <math.h>

// Problem constants (fixed by the reference file)
#define NPOINTS   8192
#define NDIM      64
#define TILE      128          // pairwise output tile per block
#define NT2       64           // NPOINTS / TILE
#define NBLK      2080         // NT2*(NT2+1)/2 triangle tiles
#define NGRP      512          // NPOINTS / 16 row-groups (prep blocks)

// ws dword/float layout:
//  [0, 262144)        W16f  : W as bf16 in MFMA-fragment order:
//                             chunk c = (rowgroup g)*2 + h  (g=row/16, h=K-half)
//                             dword addr = c*256 + lane*4 + d ; lane=quad*16+l15
//                             holds row g*16+l15, bf16 elems h*32+quad*8 .. +8
//  [262144, 393216)   W8    : W as fp8 e4m3, packed 4/dword (8192 rows x 16 dwords = 64B/row)
//  [393216, 401408)   sq    : row squared norms (fp32 exact)
//  [401408, 403488)   partA : per-tile partials of sum 1/(1+d2) over a<b  (2080)
//  [403488, 407584)   a1p   : per-pair-block partials of sum pij*log(pij*(64+d2))
//  [407584, 411680)   a3p   : per-pair-block partials of sum pij
#define WS_W16   0
#define WS_W8    262144
#define WS_SQ    393216
#define WS_PARTA 401408
#define WS_A1P   403488
#define WS_A3P   407584

typedef __attribute__((ext_vector_type(8))) short bf16x8;   // 8 bf16 = 4 VGPRs (MFMA A/B frag)
typedef __attribute__((ext_vector_type(4))) float f32x4;    // MFMA C/D frag
typedef __attribute__((ext_vector_type(2))) float f32x2;

__device__ inline unsigned f2bf_pk(float lo, float hi) {    // pack 2 fp32 -> 2 bf16 (RNE)
    unsigned ul = __float_as_uint(lo), uh = __float_as_uint(hi);
    ul += 0x7FFFu + ((ul >> 16) & 1u);
    uh += 0x7FFFu + ((uh >> 16) & 1u);
    return (ul >> 16) | (uh & 0xFFFF0000u);
}
template <bool HI>
__device__ inline f32x2 cvt2(unsigned dw) {                 // 2 fp8 e4m3 -> 2 fp32 (HW cvt)
    return __builtin_amdgcn_cvt_pk_f32_fp8((int)dw, HI);    // word-sel must be constexpr
}
__device__ inline void sqacc(f32x2& s, unsigned a, unsigned b) {  // s += (deq(a)-deq(b))^2
    f32x2 dl = cvt2<false>(a) - cvt2<false>(b);
    f32x2 dh = cvt2<true >(a) - cvt2<true >(b);
    s += dl * dl;
    s += dh * dh;
}

// One block per 16-row group g: emits (1) W16f fragment-order bf16, (2) exact
// fp32 row norms, (3) fp8 rows for the pair path. All loads/stores coalesced.
__global__ __launch_bounds__(256) void prep_kernel(const float* __restrict__ W,
                                                   float* __restrict__ sq,
                                                   unsigned* __restrict__ W16f,
                                                   unsigned* __restrict__ W8) {
    int g = blockIdx.x;
    int t = threadIdx.x;

    // ---- (1) fragment-order bf16: thread t -> (h, L, dpair), 4 floats -> uint2
    {
        int h = t >> 7, L = (t >> 1) & 63, dp = t & 1;
        int row = g * 16 + (L & 15), quad = L >> 4;
        float4 v = *(const float4*)(W + row * NDIM + h * 32 + quad * 8 + dp * 4);
        uint2 o;
        o.x = f2bf_pk(v.x, v.y);
        o.y = f2bf_pk(v.z, v.w);
        *(uint2*)(W16f + ((g * 2 + h) * 256 + L * 4 + dp * 2)) = o;
    }
    // ---- (2) exact row norms: thread t -> row r=t>>4, slice s=t&15 (4 elems)
    {
        int r = t >> 4, s = t & 15;
        float4 v = *(const float4*)(W + (g * 16 + r) * NDIM + s * 4);
        float p = v.x * v.x + v.y * v.y + v.z * v.z + v.w * v.w;
        p += __shfl_xor(p, 1, 64);
        p += __shfl_xor(p, 2, 64);
        p += __shfl_xor(p, 4, 64);
        p += __shfl_xor(p, 8, 64);
        if (s == 0) sq[g * 16 + r] = p;
    }
    // ---- (3) fp8 rows: thread t -> row t>>4, dword t&15
    {
        int r = g * 16 + (t >> 4), d = t & 15;
        float4 x = *(const float4*)(W + r * NDIM + d * 4);
        int lo = __builtin_amdgcn_cvt_pk_fp8_f32(x.x, x.y, 0, false);
        int dw = __builtin_amdgcn_cvt_pk_fp8_f32(x.z, x.w, lo, true);
        W8[r * 16 + d] = (unsigned)dw;
    }
}

// One THREAD per sampled pair, one shot: coalesced index load -> 8 independent
// dwordx4 gathers (both full fp8 rows) -> in-register decode/diff -> 1 log.
// 8 lane-requests/pair is the TA floor (r12 disproved cross-lane merging).
__global__ __launch_bounds__(256) void pair_kernel(const unsigned* __restrict__ W8,
                                                   const float* __restrict__ pij,
                                                   const int* __restrict__ ii,
                                                   const int* __restrict__ jj,
                                                   int nb,
                                                   float* __restrict__ a1p,
                                                   float* __restrict__ a3p) {
    int t = threadIdx.x;
    int p = blockIdx.x * 256 + t;
    float a1 = 0.f, a3 = 0.f;
    if (p < nb) {
        int   i  = ii[p];
        int   j  = jj[p];
        float pv = pij[p];
        const uint4* X = (const uint4*)(W8 + i * 16);
        const uint4* Y = (const uint4*)(W8 + j * 16);
        uint4 x0 = X[0], x1 = X[1], x2 = X[2], x3 = X[3];   // 8 independent 16B loads
        uint4 y0 = Y[0], y1 = Y[1], y2 = Y[2], y3 = Y[3];
        f32x2 s2 = {0.f, 0.f};
        sqacc(s2, x0.x, y0.x); sqacc(s2, x0.y, y0.y);
        sqacc(s2, x0.z, y0.z); sqacc(s2, x0.w, y0.w);
        sqacc(s2, x1.x, y1.x); sqacc(s2, x1.y, y1.y);
        sqacc(s2, x1.z, y1.z); sqacc(s2, x1.w, y1.w);
        sqacc(s2, x2.x, y2.x); sqacc(s2, x2.y, y2.y);
        sqacc(s2, x2.z, y2.z); sqacc(s2, x2.w, y2.w);
        sqacc(s2, x3.x, y3.x); sqacc(s2, x3.y, y3.y);
        sqacc(s2, x3.z, y3.z); sqacc(s2, x3.w, y3.w);
        float v = s2.x + s2.y;                              // ||xi-xj||^2
        a1 = pv * __logf(pv * ((float)NDIM + v));
        a3 = pv;
    }
    #pragma unroll
    for (int m = 32; m >= 1; m >>= 1) {
        a1 += __shfl_xor(a1, m, 64);
        a3 += __shfl_xor(a3, m, 64);
    }
    __shared__ float red[8];
    if ((t & 63) == 0) { red[t >> 6] = a1; red[4 + (t >> 6)] = a3; }
    __syncthreads();
    if (t == 0) {
        a1p[blockIdx.x] = red[0] + red[1] + red[2] + red[3];
        a3p[blockIdx.x] = red[4] + red[5] + red[6] + red[7];
    }
}

// 128x128 triangle tile of the Cauchy partition via bf16 MFMA. Fragments load
// from the pre-swizzled W16f: one dwordx4 per lane, 64 lanes CONTIGUOUS (1 KB
// per instruction, 16 sequential cache lines) — no scattered line requests.
// Frag layouts (HW-verified): A/B = X[idx=lane&15][k=(lane>>4)*8+j];
// C/D row=(lane>>4)*4+reg, col=lane&15.
__global__ __launch_bounds__(256) void pairwise_kernel(const unsigned* __restrict__ W16f,
                                                       const float* __restrict__ sq,
                                                       float* __restrict__ partA) {
    int z = blockIdx.x;
    int t = threadIdx.x, w = t >> 6, lane = t & 63;
    int by = (int)((129.0f - sqrtf((float)(16641 - 8 * z))) * 0.5f);
    while (by * NT2 - by * (by - 1) / 2 > z) --by;
    while ((by + 1) * NT2 - (by + 1) * by / 2 <= z) ++by;
    int bx = by + (z - (by * NT2 - by * (by - 1) / 2));

    int wm = w >> 1, wn = w & 1, quad = lane >> 4, l15 = lane & 15;
    int a0 = by * TILE, b0 = bx * TILE;

    float4 base1[4];                 // 1 + sq[arow + tm*16 + 0..3]
    float  sqb[4];
    {
        int arow = a0 + wm * 64 + quad * 4;
        #pragma unroll
        for (int tm = 0; tm < 4; ++tm) {
            float4 v = *(const float4*)(sq + arow + tm * 16);
            base1[tm] = (float4){1.0f + v.x, 1.0f + v.y, 1.0f + v.z, 1.0f + v.w};
        }
        int bcol = b0 + wn * 64 + l15;
        #pragma unroll
        for (int tn = 0; tn < 4; ++tn) sqb[tn] = sq[bcol + tn * 16];
    }

    f32x4 acc[4][4];
    #pragma unroll
    for (int i = 0; i < 4; ++i)
        #pragma unroll
        for (int j = 0; j < 4; ++j) acc[i][j] = (f32x4){0.f, 0.f, 0.f, 0.f};

    int gA = (a0 >> 4) + wm * 4;     // A row-groups gA+tm; B row-groups gB+tn
    int gB = (b0 >> 4) + wn * 4;
    #pragma unroll
    for (int h = 0; h < 2; ++h) {    // two K=32 halves; 1 KB contiguous per frag
        bf16x8 af[4], bfr[4];
        #pragma unroll
        for (int tm = 0; tm < 4; ++tm)
            af[tm] = *(const bf16x8*)(W16f + (((gA + tm) * 2 + h) * 256 + lane * 4));
        #pragma unroll
        for (int tn = 0; tn < 4; ++tn)
            bfr[tn] = *(const bf16x8*)(W16f + (((gB + tn) * 2 + h) * 256 + lane * 4));
        #pragma unroll
        for (int tm = 0; tm < 4; ++tm)
            #pragma unroll
            for (int tn = 0; tn < 4; ++tn)
                acc[tm][tn] = __builtin_amdgcn_mfma_f32_16x16x32_bf16(af[tm], bfr[tn],
                                                                      acc[tm][tn], 0, 0, 0);
    }

    float ssum = 0.f;
    if (bx > by) {
        #pragma unroll
        for (int tn = 0; tn < 4; ++tn) {
            float c0 = sqb[tn];
            #pragma unroll
            for (int tm = 0; tm < 4; ++tm) {
                ssum += __builtin_amdgcn_rcpf(fmaf(acc[tm][tn][0], -2.0f, base1[tm].x + c0));
                ssum += __builtin_amdgcn_rcpf(fmaf(acc[tm][tn][1], -2.0f, base1[tm].y + c0));
                ssum += __builtin_amdgcn_rcpf(fmaf(acc[tm][tn][2], -2.0f, base1[tm].z + c0));
                ssum += __builtin_amdgcn_rcpf(fmaf(acc[tm][tn][3], -2.0f, base1[tm].w + c0));
            }
        }
    } else {                         // diagonal tile: strictly-upper only
        int quad4 = quad * 4;
        #pragma unroll
        for (int tn = 0; tn < 4; ++tn) {
            int cl = wn * 64 + tn * 16 + l15;
            float c0 = sqb[tn];
            float b4[4];
            #pragma unroll
            for (int tm = 0; tm < 4; ++tm) {
                b4[0] = base1[tm].x; b4[1] = base1[tm].y;
                b4[2] = base1[tm].z; b4[3] = base1[tm].w;
                #pragma unroll
                for (int r = 0; r < 4; ++r) {
                    int rl = wm * 64 + tm * 16 + quad4 + r;
                    float inv = __builtin_amdgcn_rcpf(fmaf(acc[tm][tn][r], -2.0f, b4[r] + c0));
                    ssum += (cl > rl) ? inv : 0.f;
                }
            }
        }
    }
    #pragma unroll
    for (int m = 32; m >= 1; m >>= 1) ssum += __shfl_xor(ssum, m, 64);
    __shared__ float wsum[4];
    if (lane == 0) wsum[w] = ssum;
    __syncthreads();
    if (t == 0) partA[z] = wsum[0] + wsum[1] + wsum[2] + wsum[3];
}

__global__ __launch_bounds__(256) void final_kernel(const float* __restrict__ partA,
                                                    const float* __restrict__ a1p,
                                                    const float* __restrict__ a3p,
                                                    int npb,
                                                    float* __restrict__ out) {
    __shared__ double r1[256], r2[256], r3[256];
    int t = threadIdx.x;
    double dpart = 0.0, d1 = 0.0, d3 = 0.0;
    for (int k = t; k < NBLK; k += 256) dpart += (double)partA[k];
    for (int k = t; k < npb; k += 256) { d1 += (double)a1p[k]; d3 += (double)a3p[k]; }
    r1[t] = dpart; r2[t] = d1; r3[t] = d3;
    __syncthreads();
    for (int s = 128; s >= 1; s >>= 1) {
        if (t < s) { r1[t] += r1[t + s]; r2[t] += r2[t + s]; r3[t] += r3[t + s]; }
        __syncthreads();
    }
    if (t == 0) {
        double part = 2.0 * r1[0];                 // sum over a<b, doubled; diagonal cancels -n
        out[0] = (float)(r2[0] + r3[0] * log(part));
    }
}

extern "C" void kernel_launch(void* const* d_in, const int* in_sizes, int n_in,
                              void* d_out, int out_size, void* d_ws, size_t ws_size,
                              hipStream_t stream) {
    const float* pij = (const float*)d_in[0];
    const int*   ii  = (const int*)d_in[1];
    const int*   jj  = (const int*)d_in[2];
    const float* W   = (const float*)d_in[3];
    float* out = (float*)d_out;
    float* ws  = (float*)d_ws;

    unsigned* W16f  = (unsigned*)ws + WS_W16;
    unsigned* W8    = (unsigned*)ws + WS_W8;
    float*    sqv   = ws + WS_SQ;
    float*    partA = ws + WS_PARTA;
    float*    a1p   = ws + WS_A1P;
    float*    a3p   = ws + WS_A3P;

    int nb  = in_sizes[0];            // number of sampled pairs (B)
    int npb = (nb + 255) / 256;       // pair-kernel blocks (2048 for B=524288)

    prep_kernel<<<NGRP, 256, 0, stream>>>(W, sqv, W16f, W8);
    pair_kernel<<<npb, 256, 0, stream>>>(W8, pij, ii, jj, nb, a1p, a3p);
    pairwise_kernel<<<NBLK, 256, 0, stream>>>(W16f, sqv, partA);
    final_kernel<<<1, 256, 0, stream>>>(partA, a1p, a3p, npb, out);
}